// Round 5
// baseline (15453.368 us; speedup 1.0000x reference)
//
#include <hip/hip_runtime.h>
#include <math.h>

#define B_   64
#define T_   256
#define D_   512
#define H_   1024
#define G3_  3072
#define O_   64
#define NTOK (B_*T_)     // 16384
#define TC_  64          // timesteps per chunk
#define NCH_ 4           // chunks

// ---------------------------------------------------------------------------
// init: zero h slot 0 (fp64) and flags. grid 256 x 256.
// ---------------------------------------------------------------------------
__global__ __launch_bounds__(256) void init_ws(double* __restrict__ hs,
                                               int* __restrict__ flags)
{
  int idx = blockIdx.x*256 + threadIdx.x;   // 0..65535
  hs[idx] = 0.0;                            // slot 0 = [64][1024] doubles
  if (idx < 4096) flags[idx] = 0;
}

// ---------------------------------------------------------------------------
// Stage A (per chunk): gx[(tl*64+b)][g] = emb[x[b,t_base+tl]] . W_ih[g] + b_ih
// R3-proven 64x64 tile structure; fp32 LDS tiles (exact), fp64 FMA accum.
// Block = 64 timesteps of one batch x 64 gates. grid = 64*48 = 3072.
// ---------------------------------------------------------------------------
__global__ __launch_bounds__(256) void stage_a(
    const int* __restrict__ x, const float* __restrict__ emb,
    const float* __restrict__ W_ih, const float* __restrict__ b_ih,
    double* __restrict__ gx, int t_base)
{
  __shared__ float As[64][33];
  __shared__ float Bs[64][33];
  const int tid = threadIdx.x;
  const int b = blockIdx.x & 63, nBlk = blockIdx.x >> 6;
  const int g0 = nBlk*64;

  const int r = tid >> 2, c8 = tid & 3;     // r = t_local row / gate row
  const float* ap = emb  + (size_t)x[b*T_ + t_base + r]*D_ + c8*8;
  const float* bp = W_ih + (size_t)(g0 + r)*D_ + c8*8;
  const int tx = tid & 15, ty = tid >> 4;

  double acc[4][4];
  #pragma unroll
  for (int i = 0; i < 4; ++i)
    #pragma unroll
    for (int j = 0; j < 4; ++j) acc[i][j] = 0.0;

  float4 a0 = *(const float4*)(ap), a1 = *(const float4*)(ap + 4);
  float4 b0 = *(const float4*)(bp), b1 = *(const float4*)(bp + 4);

  for (int kb = 0; kb < 16; ++kb){
    __syncthreads();
    As[r][c8*8+0]=a0.x; As[r][c8*8+1]=a0.y; As[r][c8*8+2]=a0.z; As[r][c8*8+3]=a0.w;
    As[r][c8*8+4]=a1.x; As[r][c8*8+5]=a1.y; As[r][c8*8+6]=a1.z; As[r][c8*8+7]=a1.w;
    Bs[r][c8*8+0]=b0.x; Bs[r][c8*8+1]=b0.y; Bs[r][c8*8+2]=b0.z; Bs[r][c8*8+3]=b0.w;
    Bs[r][c8*8+4]=b1.x; Bs[r][c8*8+5]=b1.y; Bs[r][c8*8+6]=b1.z; Bs[r][c8*8+7]=b1.w;
    __syncthreads();
    if (kb < 15){
      a0 = *(const float4*)(ap + (kb+1)*32);  a1 = *(const float4*)(ap + (kb+1)*32 + 4);
      b0 = *(const float4*)(bp + (kb+1)*32);  b1 = *(const float4*)(bp + (kb+1)*32 + 4);
    }
    #pragma unroll
    for (int k = 0; k < 32; ++k){
      double av[4], bv[4];
      #pragma unroll
      for (int i = 0; i < 4; ++i) av[i] = (double)As[ty*4+i][k];
      #pragma unroll
      for (int j = 0; j < 4; ++j) bv[j] = (double)Bs[tx*4+j][k];
      #pragma unroll
      for (int i = 0; i < 4; ++i)
        #pragma unroll
        for (int j = 0; j < 4; ++j) acc[i][j] = fma(av[i], bv[j], acc[i][j]);
    }
  }

  double bi[4];
  #pragma unroll
  for (int j = 0; j < 4; ++j) bi[j] = (double)b_ih[g0 + tx*4 + j];
  #pragma unroll
  for (int i = 0; i < 4; ++i){
    int tl = ty*4 + i;
    size_t rowoff = ((size_t)tl*B_ + b)*G3_ + g0 + tx*4;
    #pragma unroll
    for (int j = 0; j < 4; ++j)
      gx[rowoff + j] = acc[i][j] + bi[j];
  }
}

// ---------------------------------------------------------------------------
// GRU recurrence (per chunk), fp64 accumulation. Persistent: 256 WGs (1/CU),
// WG wg owns h cols wg*4..+3.
//
// R5 numeric core (sync = R1-verbatim, proven):
//  - thread = (bq4 = tid>>4, k16 = tid&15): register tile 4 batches x 4 cols
//    x 3 gates over K-sixteenth [k16*64, +64). 48 FMA per double2-k from
//    4 h-reads + 3 w-reads (vs R1: 12 per 5) -> ~2.5x fewer read instrs.
//  - NO LDS: W_hh is read fp32 DIRECTLY from global (a WG's W slice = 48KB,
//    L2-resident across all 64 steps; 16 k16-lanes/instr, lines fully
//    reused step-to-step) and converted via v_cvt_f64_f32 -- lossless,
//    W is fp32 input data. Kills R1's ~15us/step LDS return-BW term.
//  - h loads: 64 distinct lanes/instr, thread-contiguous 512B k-window ->
//    dense 128B-line use, L1/L2-friendly.
//  - K-reduce: 4-stage narrowing butterfly over the k16 nibble
//    (xor 8/4/2/1), c resolved by k16>>2, batch by k16&3.
//    Lane output cell: (b_out = bq4*4 + (k16&3), c_out = i0 + (k16>>2)).
//  - Coherence unchanged (R1-validated): h(t+1) relaxed-agent stores
//    (sc0 sc1 write-through to LLC); h(t) plain cached loads (fresh slab);
//    flag store relaxed after vmcnt(0) drain + syncthreads.
// ---------------------------------------------------------------------------
__global__ __launch_bounds__(256, 1) void gru_rec(
    const float* __restrict__ W_hh, const float* __restrict__ b_hh,
    const double* __restrict__ gx, double* __restrict__ hs,
    int* __restrict__ flags, int t_base)
{
  __shared__ int abort_flag;
  const int tid = threadIdx.x, wg = blockIdx.x;
  const int i0 = wg*4;
  if (tid == 0) abort_flag = 0;

  const int bq4 = tid >> 4, k16 = tid & 15;
  const int B0  = bq4*4;
  const int cb1 = (k16 >> 3) & 1, cb0 = (k16 >> 2) & 1;
  const int bb1 = (k16 >> 1) & 1, bb0 = k16 & 1;
  const int b_out = B0 + (k16 & 3);
  const int c_out = i0 + (k16 >> 2);

  const double bh0 = (double)b_hh[c_out];
  const double bh1 = (double)b_hh[H_   + c_out];
  const double bh2 = (double)b_hh[2*H_ + c_out];

  // 12 W float4 streams for this thread's k-window (global, L2-resident)
  const float4* wp[3][4];
  #pragma unroll
  for (int p = 0; p < 3; ++p)
    #pragma unroll
    for (int c = 0; c < 4; ++c)
      wp[p][c] = (const float4*)(W_hh + (size_t)(p*H_ + i0 + c)*H_ + k16*64);

  // h_prev for this lane's owned (b_out, c_out) cell; slot 0 seeded by
  // init_ws (chunk 0) or previous gru_rec launch (kernel-boundary coherent).
  double hprev = hs[(size_t)b_out*H_ + c_out];
  __syncthreads();                           // abort_flag visible to all

  for (int tt = 0; tt < TC_; ++tt){
    const int t = t_base + tt;

    // gx is pre-kernel data (stage_a): load BEFORE the spin, hide under it.
    const double* gp = gx + ((size_t)tt*B_ + b_out)*G3_ + c_out;
    double gxr = gp[0];
    double gxz = gp[H_];
    double gxn = gp[2*H_];

    {                                        // R1-verbatim poll
      int* fp = flags + tid*16;
      int gcnt = 0;
      while (__hip_atomic_load(fp, __ATOMIC_RELAXED, __HIP_MEMORY_SCOPE_AGENT) < t){
        __builtin_amdgcn_s_sleep(2);
        if (++gcnt > (1<<18)) { abort_flag = 1; break; }   // fail-soft
      }
    }
    __syncthreads();                         // releases WG; blocks h-load hoist
    if (abort_flag) break;                   // WG-uniform: all threads bail

    const double2* hp[4];
    #pragma unroll
    for (int bi = 0; bi < 4; ++bi)
      hp[bi] = (const double2*)(hs + ((size_t)tt*B_ + B0 + bi)*H_ + k16*64);

    double P[4][4][3];                       // [bi][c][gate]
    #pragma unroll
    for (int bi = 0; bi < 4; ++bi)
      #pragma unroll
      for (int c = 0; c < 4; ++c)
        #pragma unroll
        for (int p = 0; p < 3; ++p) P[bi][c][p] = 0.0;

    #pragma unroll 2
    for (int g4 = 0; g4 < 16; ++g4){
      double2 h0[4], h1[4];
      #pragma unroll
      for (int bi = 0; bi < 4; ++bi){
        h0[bi] = hp[bi][2*g4];               // k = 4g4, 4g4+1
        h1[bi] = hp[bi][2*g4+1];             // k = 4g4+2, 4g4+3
      }
      float4 wv[3][4];
      #pragma unroll
      for (int p = 0; p < 3; ++p)
        #pragma unroll
        for (int c = 0; c < 4; ++c) wv[p][c] = wp[p][c][g4];

      #pragma unroll
      for (int p = 0; p < 3; ++p)
        #pragma unroll
        for (int c = 0; c < 4; ++c){
          double w0 = (double)wv[p][c].x;
          double w1 = (double)wv[p][c].y;
          double w2 = (double)wv[p][c].z;
          double w3 = (double)wv[p][c].w;
          #pragma unroll
          for (int bi = 0; bi < 4; ++bi){
            double a = P[bi][c][p];
            a = fma(h0[bi].x, w0, a);
            a = fma(h0[bi].y, w1, a);
            a = fma(h1[bi].x, w2, a);
            a = fma(h1[bi].y, w3, a);
            P[bi][c][p] = a;
          }
        }
    }

    // ---- 4-stage narrowing butterfly over the k16 nibble ----
    // S1: xor 8 (c bit1)
    #pragma unroll
    for (int bi = 0; bi < 4; ++bi)
      #pragma unroll
      for (int c = 0; c < 4; ++c)
        #pragma unroll
        for (int p = 0; p < 3; ++p)
          P[bi][c][p] += __shfl_xor(P[bi][c][p], 8);
    double L24[4][2][3];
    #pragma unroll
    for (int bi = 0; bi < 4; ++bi)
      #pragma unroll
      for (int dc = 0; dc < 2; ++dc)
        #pragma unroll
        for (int p = 0; p < 3; ++p)
          L24[bi][dc][p] = cb1 ? P[bi][2+dc][p] : P[bi][dc][p];
    // S2: xor 4 (c bit0)
    #pragma unroll
    for (int bi = 0; bi < 4; ++bi)
      #pragma unroll
      for (int dc = 0; dc < 2; ++dc)
        #pragma unroll
        for (int p = 0; p < 3; ++p)
          L24[bi][dc][p] += __shfl_xor(L24[bi][dc][p], 4);
    double L12[4][3];
    #pragma unroll
    for (int bi = 0; bi < 4; ++bi)
      #pragma unroll
      for (int p = 0; p < 3; ++p)
        L12[bi][p] = cb0 ? L24[bi][1][p] : L24[bi][0][p];
    // S3: xor 2 (bi bit1)
    #pragma unroll
    for (int bi = 0; bi < 4; ++bi)
      #pragma unroll
      for (int p = 0; p < 3; ++p)
        L12[bi][p] += __shfl_xor(L12[bi][p], 2);
    double L6[2][3];
    #pragma unroll
    for (int db = 0; db < 2; ++db)
      #pragma unroll
      for (int p = 0; p < 3; ++p)
        L6[db][p] = bb1 ? L12[2+db][p] : L12[db][p];
    // S4: xor 1 (bi bit0)
    #pragma unroll
    for (int db = 0; db < 2; ++db)
      #pragma unroll
      for (int p = 0; p < 3; ++p)
        L6[db][p] += __shfl_xor(L6[db][p], 1);
    double sg0 = bb0 ? L6[1][0] : L6[0][0];
    double sg1 = bb0 ? L6[1][1] : L6[0][1];
    double sg2 = bb0 ? L6[1][2] : L6[0][2];

    double rr_ = 1.0/(1.0 + exp(-(gxr + sg0 + bh0)));
    double zz  = 1.0/(1.0 + exp(-(gxz + sg1 + bh1)));
    double nn  = tanh(gxn + rr_*(sg2 + bh2));
    double hnew = (1.0 - zz)*nn + zz*hprev;
    hprev = hnew;

    // LLC-direct (sc0 sc1) stores: agent-visible without any release fence.
    __hip_atomic_store(&hs[((size_t)(tt+1)*B_ + b_out)*H_ + c_out], hnew,
                       __ATOMIC_RELAXED, __HIP_MEMORY_SCOPE_AGENT);
    if (tt == TC_-1)
      __hip_atomic_store(&hs[(size_t)b_out*H_ + c_out], hnew,
                         __ATOMIC_RELAXED, __HIP_MEMORY_SCOPE_AGENT);

    asm volatile("s_waitcnt vmcnt(0)" ::: "memory");  // stores acked at LLC
    __syncthreads();                                  // all 4 waves drained
    if (tid == 0)
      __hip_atomic_store(flags + wg*16, t+1, __ATOMIC_RELAXED, __HIP_MEMORY_SCOPE_AGENT);
  }
}

// ---------------------------------------------------------------------------
// FC + sigmoid + labels (per chunk). fp64 accumulation.
// Labels emulate an fp32 sigmoid+threshold: pf = 1/(1+exp32(-logit32)),
// label = pf > 0.5f. (exp32 emulated as correctly-rounded via fp64 exp.)
// Block = batch b: 64 timesteps x 64 outputs, K=1024. grid 64.
// ---------------------------------------------------------------------------
__global__ __launch_bounds__(256) void fc_out(
    const double* __restrict__ hs, const float* __restrict__ W_fc,
    const float* __restrict__ b_fc, float* __restrict__ out, int t_base)
{
  __shared__ double Ah[64][34];
  __shared__ double Bw[64][34];
  const int tid = threadIdx.x;
  const int b = blockIdx.x;
  const int r = tid >> 2, c8 = tid & 3;
  const double* ap = hs   + ((size_t)(r+1)*B_ + b)*H_ + c8*8;   // slot = tl+1
  const float*  bp = W_fc + (size_t)r*H_ + c8*8;
  const int tx = tid & 15, ty = tid >> 4;

  double acc[4][4];
  #pragma unroll
  for (int i = 0; i < 4; ++i)
    #pragma unroll
    for (int j = 0; j < 4; ++j) acc[i][j] = 0.0;

  double ar0[8]; float br0[8];
  #pragma unroll
  for (int e = 0; e < 8; ++e){ ar0[e] = ap[e]; br0[e] = bp[e]; }

  for (int kb = 0; kb < 32; ++kb){
    __syncthreads();
    #pragma unroll
    for (int e = 0; e < 8; ++e){
      Ah[r][c8*8+e] = ar0[e];
      Bw[r][c8*8+e] = (double)br0[e];
    }
    __syncthreads();
    if (kb < 31){
      #pragma unroll
      for (int e = 0; e < 8; ++e){
        ar0[e] = ap[(kb+1)*32 + e];
        br0[e] = bp[(kb+1)*32 + e];
      }
    }
    #pragma unroll
    for (int k = 0; k < 32; ++k){
      double av[4], bv[4];
      #pragma unroll
      for (int i = 0; i < 4; ++i) av[i] = Ah[ty*4+i][k];
      #pragma unroll
      for (int j = 0; j < 4; ++j) bv[j] = Bw[tx*4+j][k];
      #pragma unroll
      for (int i = 0; i < 4; ++i)
        #pragma unroll
        for (int j = 0; j < 4; ++j) acc[i][j] = fma(av[i], bv[j], acc[i][j]);
    }
  }

  double bi[4];
  #pragma unroll
  for (int j = 0; j < 4; ++j) bi[j] = (double)b_fc[tx*4 + j];
  #pragma unroll
  for (int i = 0; i < 4; ++i){
    int tl = ty*4 + i;
    size_t tok = (size_t)b*T_ + t_base + tl;
    float4 pr, lb;
    float* prp = (float*)&pr; float* lbp = (float*)&lb;
    #pragma unroll
    for (int j = 0; j < 4; ++j){
      double logit = acc[i][j] + bi[j];
      prp[j] = (float)(1.0/(1.0 + exp(-logit)));
      // fp32-sigmoid-emulated label rule:
      float lf = (float)logit;                    // fp32 logit
      float ef = (float)exp(-(double)lf);         // correctly-rounded fp32 exp
      float pf = 1.0f / (1.0f + ef);              // fp32 ops thereafter
      lbp[j] = (pf > 0.5f) ? 1.0f : 0.0f;
    }
    *(float4*)&out[tok*O_ + tx*4] = pr;
    *(float4*)&out[(size_t)NTOK*O_ + tok*O_ + tx*4] = lb;
  }
}

// ---------------------------------------------------------------------------
extern "C" void kernel_launch(void* const* d_in, const int* in_sizes, int n_in,
                              void* d_out, int out_size, void* d_ws, size_t ws_size,
                              hipStream_t stream) {
  const int*   x    = (const int*)  d_in[0];
  const float* emb  = (const float*)d_in[1];
  const float* W_ih = (const float*)d_in[2];
  const float* W_hh = (const float*)d_in[3];
  const float* b_ih = (const float*)d_in[4];
  const float* b_hh = (const float*)d_in[5];
  const float* W_fc = (const float*)d_in[6];
  const float* b_fc = (const float*)d_in[7];
  float* out = (float*)d_out;
  char* ws = (char*)d_ws;

  // ws layout (bytes) — total 134,758,400
  double* gx    = (double*)(ws);                 // 64*64*3072*8  = 100,663,296
  double* hs    = (double*)(ws + 100663296);     // 65*64*1024*8  =  34,078,720
  int*    flags = (int*)   (ws + 134742016);     // 16,384

  hipLaunchKernelGGL(init_ws, dim3(256), dim3(256), 0, stream, hs, flags);
  for (int c = 0; c < NCH_; ++c){
    int t_base = c*TC_;
    hipLaunchKernelGGL(stage_a, dim3(3072), dim3(256), 0, stream,
                       x, emb, W_ih, b_ih, gx, t_base);
    hipLaunchKernelGGL(gru_rec, dim3(256), dim3(256), 0, stream,
                       W_hh, b_hh, gx, hs, flags, t_base);
    hipLaunchKernelGGL(fc_out, dim3(64), dim3(256), 0, stream,
                       hs, W_fc, b_fc, out, t_base);
  }
}

// Round 6
// 10399.548 us; speedup vs baseline: 1.4860x; 1.4860x over previous
//
#include <hip/hip_runtime.h>
#include <math.h>

#define B_   64
#define T_   256
#define D_   512
#define H_   1024
#define G3_  3072
#define O_   64
#define NTOK (B_*T_)     // 16384
#define TC_  64          // timesteps per chunk
#define NCH_ 4           // chunks

// ---------------------------------------------------------------------------
// init: zero h slot 0 (fp64) and flags. grid 256 x 256.
// ---------------------------------------------------------------------------
__global__ __launch_bounds__(256) void init_ws(double* __restrict__ hs,
                                               int* __restrict__ flags)
{
  int idx = blockIdx.x*256 + threadIdx.x;   // 0..65535
  hs[idx] = 0.0;                            // slot 0 = [64][1024] doubles
  if (idx < 4096) flags[idx] = 0;
}

// ---------------------------------------------------------------------------
// Stage A (per chunk): gx[(tl*64+b)][g] = emb[x[b,t_base+tl]] . W_ih[g] + b_ih
// R3-proven 64x64 tile structure; fp32 LDS tiles (exact), fp64 FMA accum.
// Block = 64 timesteps of one batch x 64 gates. grid = 64*48 = 3072.
// ---------------------------------------------------------------------------
__global__ __launch_bounds__(256) void stage_a(
    const int* __restrict__ x, const float* __restrict__ emb,
    const float* __restrict__ W_ih, const float* __restrict__ b_ih,
    double* __restrict__ gx, int t_base)
{
  __shared__ float As[64][33];
  __shared__ float Bs[64][33];
  const int tid = threadIdx.x;
  const int b = blockIdx.x & 63, nBlk = blockIdx.x >> 6;
  const int g0 = nBlk*64;

  const int r = tid >> 2, c8 = tid & 3;     // r = t_local row / gate row
  const float* ap = emb  + (size_t)x[b*T_ + t_base + r]*D_ + c8*8;
  const float* bp = W_ih + (size_t)(g0 + r)*D_ + c8*8;
  const int tx = tid & 15, ty = tid >> 4;

  double acc[4][4];
  #pragma unroll
  for (int i = 0; i < 4; ++i)
    #pragma unroll
    for (int j = 0; j < 4; ++j) acc[i][j] = 0.0;

  float4 a0 = *(const float4*)(ap), a1 = *(const float4*)(ap + 4);
  float4 b0 = *(const float4*)(bp), b1 = *(const float4*)(bp + 4);

  for (int kb = 0; kb < 16; ++kb){
    __syncthreads();
    As[r][c8*8+0]=a0.x; As[r][c8*8+1]=a0.y; As[r][c8*8+2]=a0.z; As[r][c8*8+3]=a0.w;
    As[r][c8*8+4]=a1.x; As[r][c8*8+5]=a1.y; As[r][c8*8+6]=a1.z; As[r][c8*8+7]=a1.w;
    Bs[r][c8*8+0]=b0.x; Bs[r][c8*8+1]=b0.y; Bs[r][c8*8+2]=b0.z; Bs[r][c8*8+3]=b0.w;
    Bs[r][c8*8+4]=b1.x; Bs[r][c8*8+5]=b1.y; Bs[r][c8*8+6]=b1.z; Bs[r][c8*8+7]=b1.w;
    __syncthreads();
    if (kb < 15){
      a0 = *(const float4*)(ap + (kb+1)*32);  a1 = *(const float4*)(ap + (kb+1)*32 + 4);
      b0 = *(const float4*)(bp + (kb+1)*32);  b1 = *(const float4*)(bp + (kb+1)*32 + 4);
    }
    #pragma unroll
    for (int k = 0; k < 32; ++k){
      double av[4], bv[4];
      #pragma unroll
      for (int i = 0; i < 4; ++i) av[i] = (double)As[ty*4+i][k];
      #pragma unroll
      for (int j = 0; j < 4; ++j) bv[j] = (double)Bs[tx*4+j][k];
      #pragma unroll
      for (int i = 0; i < 4; ++i)
        #pragma unroll
        for (int j = 0; j < 4; ++j) acc[i][j] = fma(av[i], bv[j], acc[i][j]);
    }
  }

  double bi[4];
  #pragma unroll
  for (int j = 0; j < 4; ++j) bi[j] = (double)b_ih[g0 + tx*4 + j];
  #pragma unroll
  for (int i = 0; i < 4; ++i){
    int tl = ty*4 + i;
    size_t rowoff = ((size_t)tl*B_ + b)*G3_ + g0 + tx*4;
    #pragma unroll
    for (int j = 0; j < 4; ++j)
      gx[rowoff + j] = acc[i][j] + bi[j];
  }
}

// ---------------------------------------------------------------------------
// GRU recurrence (per chunk), fp64 accumulation. Persistent: 256 WGs (1/CU),
// WG wg owns h cols wg*4..+3.
//
// R6 = R1-validated core with ONE in-place delta: W lives in LDS as FP32
// (W_hh IS fp32 input data; v_cvt_f64_f32 at use is exact -> results are
// bitwise identical to the fp64-LDS version). Read as float4 (4 k / 16B):
//  - LDS W-traffic per CU per step: 3 MB -> 0.75 MB (was ~10us of the
//    33us step at 128 B/cyc; now ~2.6us). W-read instrs 768 -> 384.
//  - Thread map, 2 global h-streams (double2, same window), 16-k unroll
//    window, reduce, and sync protocol are R1-VERBATIM (R2/R5 lesson:
//    restructures of this loop regress; only in-place deltas).
//  - Wf rows = 516 floats (2064 B = 129 x 16B-quads, 129 = 1 mod 8):
//    the 8 distinct (j,half) row addresses per gate-read map to 8 distinct
//    bank-quads -> conflict-free b128 reads.
//  - Coherence scheme unchanged (R1-validated fence-free LLC):
//    h(t+1) relaxed-agent stores (sc0 sc1 write-through to LLC);
//    h(t) plain cached loads (fresh slab each step);
//    flag store relaxed after explicit vmcnt(0) drain + syncthreads;
//    all-thread poll (thread tid polls WG tid's flag), s_sleep backoff.
// Flags carry GLOBAL step count (monotone across chunks). Bounded spin with
// WG-uniform abort (fail-soft).
// ---------------------------------------------------------------------------
__global__ __launch_bounds__(256, 1) void gru_rec(
    const float* __restrict__ W_hh, const float* __restrict__ b_hh,
    const double* __restrict__ gx, double* __restrict__ hs,
    int* __restrict__ flags, int t_base)
{
  __shared__ float Wf[2*12*516];             // 49,536 B; [half][rr=p*4+j][516]
  __shared__ int abort_flag;
  const int tid = threadIdx.x, wg = blockIdx.x;
  const int i0 = wg*4;
  if (tid == 0) abort_flag = 0;

  for (int it = tid; it < 12*1024; it += 256){
    int rr = it >> 10, k = it & 1023;
    int p = rr >> 2, j = rr & 3;
    int hf = k >> 9, kl = k & 511;
    Wf[(hf*12 + rr)*516 + kl] = W_hh[(size_t)(p*H_ + i0 + j)*H_ + k];
  }

  const int bq = tid >> 3, j = (tid >> 1) & 3, half = tid & 1;
  const int b_out = bq*2 + half;
  const int jj = i0 + j;
  const double bh0 = (double)b_hh[jj];
  const double bh1 = (double)b_hh[H_   + jj];
  const double bh2 = (double)b_hh[2*H_ + jj];
  const float4* w0p = (const float4*)&Wf[(half*12 + 0*4 + j)*516];
  const float4* w1p = (const float4*)&Wf[(half*12 + 1*4 + j)*516];
  const float4* w2p = (const float4*)&Wf[(half*12 + 2*4 + j)*516];
  __syncthreads();

  // h_prev for this thread's own (b_out, jj) cell; slot 0 seeded by
  // init_ws (chunk 0) or previous gru_rec launch (kernel-boundary coherent).
  double hprev = hs[(size_t)b_out*H_ + jj];

  for (int tt = 0; tt < TC_; ++tt){
    const int t = t_base + tt;

    // gx is pre-kernel data (stage_a): load BEFORE the spin, hide under it.
    const double* gp = gx + ((size_t)tt*B_ + b_out)*G3_ + jj;
    double gxr = gp[0];
    double gxz = gp[H_];
    double gxn = gp[2*H_];

    {                                        // R1-verbatim all-thread poll
      int* fp = flags + tid*16;
      int gcnt = 0;
      while (__hip_atomic_load(fp, __ATOMIC_RELAXED, __HIP_MEMORY_SCOPE_AGENT) < t){
        __builtin_amdgcn_s_sleep(2);
        if (++gcnt > (1<<18)) { abort_flag = 1; break; }   // fail-soft
      }
    }
    __syncthreads();                         // releases WG; blocks h-load hoist
    if (abort_flag) break;                   // WG-uniform: all threads bail

    const double2* h0 = (const double2*)(hs + ((size_t)tt*B_ + bq*2    )*H_ + half*512);
    const double2* h1 = (const double2*)(hs + ((size_t)tt*B_ + bq*2 + 1)*H_ + half*512);

    double pr00=0.0, pr10=0.0, pr20=0.0, pr01=0.0, pr11=0.0, pr21=0.0;
    // 128 iters x 4 k each; unroll 4 = same 16-k scheduling window as R1.
    #pragma unroll 4
    for (int kk = 0; kk < 128; ++kk){
      double2 a00 = h0[2*kk], a01 = h0[2*kk+1];
      double2 a10 = h1[2*kk], a11 = h1[2*kk+1];
      float4 w0 = w0p[kk];
      float4 w1 = w1p[kk];
      float4 w2 = w2p[kk];
      double w0x=(double)w0.x, w0y=(double)w0.y, w0z=(double)w0.z, w0w=(double)w0.w;
      double w1x=(double)w1.x, w1y=(double)w1.y, w1z=(double)w1.z, w1w=(double)w1.w;
      double w2x=(double)w2.x, w2y=(double)w2.y, w2z=(double)w2.z, w2w=(double)w2.w;
      pr00 = fma(a00.x, w0x, pr00); pr00 = fma(a00.y, w0y, pr00);
      pr00 = fma(a01.x, w0z, pr00); pr00 = fma(a01.y, w0w, pr00);
      pr10 = fma(a00.x, w1x, pr10); pr10 = fma(a00.y, w1y, pr10);
      pr10 = fma(a01.x, w1z, pr10); pr10 = fma(a01.y, w1w, pr10);
      pr20 = fma(a00.x, w2x, pr20); pr20 = fma(a00.y, w2y, pr20);
      pr20 = fma(a01.x, w2z, pr20); pr20 = fma(a01.y, w2w, pr20);
      pr01 = fma(a10.x, w0x, pr01); pr01 = fma(a10.y, w0y, pr01);
      pr01 = fma(a11.x, w0z, pr01); pr01 = fma(a11.y, w0w, pr01);
      pr11 = fma(a10.x, w1x, pr11); pr11 = fma(a10.y, w1y, pr11);
      pr11 = fma(a11.x, w1z, pr11); pr11 = fma(a11.y, w1w, pr11);
      pr21 = fma(a10.x, w2x, pr21); pr21 = fma(a10.y, w2y, pr21);
      pr21 = fma(a11.x, w2z, pr21); pr21 = fma(a11.y, w2w, pr21);
    }
    double s00 = pr00 + __shfl_xor(pr00, 1);
    double s01 = pr01 + __shfl_xor(pr01, 1);
    double s10 = pr10 + __shfl_xor(pr10, 1);
    double s11 = pr11 + __shfl_xor(pr11, 1);
    double s20 = pr20 + __shfl_xor(pr20, 1);
    double s21 = pr21 + __shfl_xor(pr21, 1);
    double ar = half ? s01 : s00;
    double az = half ? s11 : s10;
    double an = half ? s21 : s20;

    double rr_ = 1.0/(1.0 + exp(-(gxr + ar + bh0)));
    double zz  = 1.0/(1.0 + exp(-(gxz + az + bh1)));
    double nn  = tanh(gxn + rr_*(an + bh2));
    double hnew = (1.0 - zz)*nn + zz*hprev;
    hprev = hnew;

    // LLC-direct (sc0 sc1) stores: agent-visible without any release fence.
    __hip_atomic_store(&hs[((size_t)(tt+1)*B_ + b_out)*H_ + jj], hnew,
                       __ATOMIC_RELAXED, __HIP_MEMORY_SCOPE_AGENT);
    if (tt == TC_-1)
      __hip_atomic_store(&hs[(size_t)b_out*H_ + jj], hnew,
                         __ATOMIC_RELAXED, __HIP_MEMORY_SCOPE_AGENT);

    asm volatile("s_waitcnt vmcnt(0)" ::: "memory");  // stores acked at LLC
    __syncthreads();                                  // all 4 waves drained
    if (tid == 0)
      __hip_atomic_store(flags + wg*16, t+1, __ATOMIC_RELAXED, __HIP_MEMORY_SCOPE_AGENT);
  }
}

// ---------------------------------------------------------------------------
// FC + sigmoid + labels (per chunk). fp64 accumulation.
// Labels emulate an fp32 sigmoid+threshold: pf = 1/(1+exp32(-logit32)),
// label = pf > 0.5f. (exp32 emulated as correctly-rounded via fp64 exp.)
// Block = batch b: 64 timesteps x 64 outputs, K=1024. grid 64.
// ---------------------------------------------------------------------------
__global__ __launch_bounds__(256) void fc_out(
    const double* __restrict__ hs, const float* __restrict__ W_fc,
    const float* __restrict__ b_fc, float* __restrict__ out, int t_base)
{
  __shared__ double Ah[64][34];
  __shared__ double Bw[64][34];
  const int tid = threadIdx.x;
  const int b = blockIdx.x;
  const int r = tid >> 2, c8 = tid & 3;
  const double* ap = hs   + ((size_t)(r+1)*B_ + b)*H_ + c8*8;   // slot = tl+1
  const float*  bp = W_fc + (size_t)r*H_ + c8*8;
  const int tx = tid & 15, ty = tid >> 4;

  double acc[4][4];
  #pragma unroll
  for (int i = 0; i < 4; ++i)
    #pragma unroll
    for (int j = 0; j < 4; ++j) acc[i][j] = 0.0;

  double ar0[8]; float br0[8];
  #pragma unroll
  for (int e = 0; e < 8; ++e){ ar0[e] = ap[e]; br0[e] = bp[e]; }

  for (int kb = 0; kb < 32; ++kb){
    __syncthreads();
    #pragma unroll
    for (int e = 0; e < 8; ++e){
      Ah[r][c8*8+e] = ar0[e];
      Bw[r][c8*8+e] = (double)br0[e];
    }
    __syncthreads();
    if (kb < 31){
      #pragma unroll
      for (int e = 0; e < 8; ++e){
        ar0[e] = ap[(kb+1)*32 + e];
        br0[e] = bp[(kb+1)*32 + e];
      }
    }
    #pragma unroll
    for (int k = 0; k < 32; ++k){
      double av[4], bv[4];
      #pragma unroll
      for (int i = 0; i < 4; ++i) av[i] = Ah[ty*4+i][k];
      #pragma unroll
      for (int j = 0; j < 4; ++j) bv[j] = Bw[tx*4+j][k];
      #pragma unroll
      for (int i = 0; i < 4; ++i)
        #pragma unroll
        for (int j = 0; j < 4; ++j) acc[i][j] = fma(av[i], bv[j], acc[i][j]);
    }
  }

  double bi[4];
  #pragma unroll
  for (int j = 0; j < 4; ++j) bi[j] = (double)b_fc[tx*4 + j];
  #pragma unroll
  for (int i = 0; i < 4; ++i){
    int tl = ty*4 + i;
    size_t tok = (size_t)b*T_ + t_base + tl;
    float4 pr, lb;
    float* prp = (float*)&pr; float* lbp = (float*)&lb;
    #pragma unroll
    for (int j = 0; j < 4; ++j){
      double logit = acc[i][j] + bi[j];
      prp[j] = (float)(1.0/(1.0 + exp(-logit)));
      // fp32-sigmoid-emulated label rule:
      float lf = (float)logit;                    // fp32 logit
      float ef = (float)exp(-(double)lf);         // correctly-rounded fp32 exp
      float pf = 1.0f / (1.0f + ef);              // fp32 ops thereafter
      lbp[j] = (pf > 0.5f) ? 1.0f : 0.0f;
    }
    *(float4*)&out[tok*O_ + tx*4] = pr;
    *(float4*)&out[(size_t)NTOK*O_ + tok*O_ + tx*4] = lb;
  }
}

// ---------------------------------------------------------------------------
extern "C" void kernel_launch(void* const* d_in, const int* in_sizes, int n_in,
                              void* d_out, int out_size, void* d_ws, size_t ws_size,
                              hipStream_t stream) {
  const int*   x    = (const int*)  d_in[0];
  const float* emb  = (const float*)d_in[1];
  const float* W_ih = (const float*)d_in[2];
  const float* W_hh = (const float*)d_in[3];
  const float* b_ih = (const float*)d_in[4];
  const float* b_hh = (const float*)d_in[5];
  const float* W_fc = (const float*)d_in[6];
  const float* b_fc = (const float*)d_in[7];
  float* out = (float*)d_out;
  char* ws = (char*)d_ws;

  // ws layout (bytes) — total 134,758,400
  double* gx    = (double*)(ws);                 // 64*64*3072*8  = 100,663,296
  double* hs    = (double*)(ws + 100663296);     // 65*64*1024*8  =  34,078,720
  int*    flags = (int*)   (ws + 134742016);     // 16,384

  hipLaunchKernelGGL(init_ws, dim3(256), dim3(256), 0, stream, hs, flags);
  for (int c = 0; c < NCH_; ++c){
    int t_base = c*TC_;
    hipLaunchKernelGGL(stage_a, dim3(3072), dim3(256), 0, stream,
                       x, emb, W_ih, b_ih, gx, t_base);
    hipLaunchKernelGGL(gru_rec, dim3(256), dim3(256), 0, stream,
                       W_hh, b_hh, gx, hs, flags, t_base);
    hipLaunchKernelGGL(fc_out, dim3(64), dim3(256), 0, stream,
                       hs, W_fc, b_fc, out, t_base);
  }
}